// Round 1
// baseline (192.478 us; speedup 1.0000x reference)
//
#include <hip/hip_runtime.h>
#include <hip/hip_bf16.h>

// Problem constants
#define BATCH   256
#define NP      196
#define HIDDEN  1024
#define ATT     512
#define M_TOTAL (BATCH * NP)   // 50176 rows, divisible by 64 (784 blocks)

typedef __attribute__((ext_vector_type(8))) short bf16x8v;  // 8 bf16 = 4 VGPR
typedef __attribute__((ext_vector_type(4))) float f32x4;

// f32 -> bf16 with round-to-nearest-even
__device__ inline unsigned short f2bf(float x) {
    unsigned int u = __float_as_uint(x);
    u += 0x7fffu + ((u >> 16) & 1u);
    return (unsigned short)(u >> 16);
}

__device__ inline float fast_tanh(float x) {
    // tanh(x) = 1 - 2/(e^{2x}+1); saturates correctly at +-inf
    float e = __expf(2.0f * x);
    return 1.0f - 2.0f / (e + 1.0f);
}

// ---------------------------------------------------------------------------
// K0: rearrange W_cnn (f32 [1024][512]) into bf16 k-tiles laid out exactly as
// the K2 LDS B-buffer wants them:
//   Wt[kt][chunk][n][8k], kt=0..31 (K-tile of 32), chunk=0..3 (8k each), n=0..511
// slot id g in [0, 65536); each slot holds 8 bf16 (16B).
// ---------------------------------------------------------------------------
__global__ void k0_arrange(const float* __restrict__ Wc, unsigned short* __restrict__ Wt) {
    int g = blockIdx.x * 256 + threadIdx.x;      // 65536 slots
    int kt    = g >> 11;                          // 2048 slots per k-tile
    int slot  = g & 2047;
    int chunk = slot >> 9;
    int n     = slot & 511;
    int kb = kt * 32 + chunk * 8;
    unsigned short v[8];
#pragma unroll
    for (int j = 0; j < 8; ++j) v[j] = f2bf(Wc[(kb + j) * ATT + n]);
    uint4 pk;
    pk.x = (unsigned int)v[0] | ((unsigned int)v[1] << 16);
    pk.y = (unsigned int)v[2] | ((unsigned int)v[3] << 16);
    pk.z = (unsigned int)v[4] | ((unsigned int)v[5] << 16);
    pk.w = (unsigned int)v[6] | ((unsigned int)v[7] << 16);
    *(uint4*)(Wt + (size_t)g * 8) = pk;
}

// ---------------------------------------------------------------------------
// K1: dec_out = decoder_out @ W_dec ; stw = st @ W_sen   (f32, exactish)
// grid (4 col-quarters, 32 b-octets, 2 mats), block 256.
// thread: 1 b, 4 consecutive cols (float4 weight loads, coalesced).
// ---------------------------------------------------------------------------
__global__ void k1_small(const float* __restrict__ dec_in, const float* __restrict__ st,
                         const float* __restrict__ Wdec,  const float* __restrict__ Wsen,
                         float* __restrict__ dec_out, float* __restrict__ stw) {
    const float* X = blockIdx.z ? st   : dec_in;
    const float* W = blockIdx.z ? Wsen : Wdec;
    float*       O = blockIdx.z ? stw  : dec_out;
    int ci = threadIdx.x & 31;
    int c0 = blockIdx.x * 128 + ci * 4;
    int b  = blockIdx.y * 8 + (threadIdx.x >> 5);
    const float* x = X + (size_t)b * HIDDEN;
    float4 acc = {0.f, 0.f, 0.f, 0.f};
    for (int k = 0; k < HIDDEN; k += 4) {
#pragma unroll
        for (int kk = 0; kk < 4; ++kk) {
            float4 w = *(const float4*)(W + (size_t)(k + kk) * ATT + c0);
            float a = x[k + kk];
            acc.x += a * w.x; acc.y += a * w.y; acc.z += a * w.z; acc.w += a * w.w;
        }
    }
    *(float4*)(O + (size_t)b * ATT + c0) = acc;
}

// ---------------------------------------------------------------------------
// K2: fused  zt[r] = sum_a tanh( (A@Wc)[r,a] + dec[b(r),a] ) * Watt[a]
// A = spatial as [50176][1024] f32. bf16 MFMA 16x16x32, f32 accum.
// Block: 64 rows x 512 cols (all of N), 8 waves (wave w owns cols w*64..+64).
// A reg-staged f32->bf16 into LDS [chunk][row][8k]; B from pre-tiled Wt
// (contiguous coalesced loads). Deterministic in-block zt reduction.
// ---------------------------------------------------------------------------
__global__ void __launch_bounds__(512)
k2_fused_gemm(const float* __restrict__ A, const unsigned short* __restrict__ Wt,
              const float* __restrict__ dec, const float* __restrict__ Watt,
              float* __restrict__ zt) {
    __shared__ __align__(16) unsigned short Abuf[4 * 64 * 8];    //  4 KB
    __shared__ __align__(16) unsigned short Bbuf[4 * 512 * 8];   // 32 KB
    __shared__ float zred[64 * 8];                               //  2 KB

    const int tid = threadIdx.x;
    const int w = tid >> 6;          // wave 0..7
    const int l = tid & 63;          // lane
    const int lg = l >> 4, ll = l & 15;
    const int r0 = blockIdx.x * 64;

    f32x4 acc[4][4];
#pragma unroll
    for (int m = 0; m < 4; ++m)
#pragma unroll
        for (int n = 0; n < 4; ++n) acc[m][n] = (f32x4){0.f, 0.f, 0.f, 0.f};

    // A staging assignment: thread -> (row, 4 consecutive k) ; 64 rows x 32 k
    const int arow = tid >> 3;
    const int akp  = tid & 7;
    const float* aptr = A + (size_t)(r0 + arow) * HIDDEN + akp * 4;
    const int aslot = (((akp >> 1) * 64 + arow) << 3) + (akp & 1) * 4;  // element idx

    for (int kt = 0; kt < 32; ++kt) {
        // global loads for this K-step (before barrier: no LDS dependence)
        float4 av = *(const float4*)(aptr + kt * 32);
        const uint4* bsrc = (const uint4*)(Wt + (size_t)kt * 16384);
        uint4 bv0 = bsrc[tid];
        uint4 bv1 = bsrc[512 + tid];
        uint4 bv2 = bsrc[1024 + tid];
        uint4 bv3 = bsrc[1536 + tid];

        __syncthreads();   // previous tile fully consumed

        uint2 pk;
        pk.x = (unsigned int)f2bf(av.x) | ((unsigned int)f2bf(av.y) << 16);
        pk.y = (unsigned int)f2bf(av.z) | ((unsigned int)f2bf(av.w) << 16);
        *(uint2*)(Abuf + aslot) = pk;
        ((uint4*)Bbuf)[tid]        = bv0;
        ((uint4*)Bbuf)[512 + tid]  = bv1;
        ((uint4*)Bbuf)[1024 + tid] = bv2;
        ((uint4*)Bbuf)[1536 + tid] = bv3;

        __syncthreads();   // tile visible

        bf16x8v af[4], bfr[4];
#pragma unroll
        for (int m = 0; m < 4; ++m)
            af[m] = *(const bf16x8v*)(Abuf + ((lg * 64 + m * 16 + ll) << 3));
#pragma unroll
        for (int n = 0; n < 4; ++n)
            bfr[n] = *(const bf16x8v*)(Bbuf + ((lg * 512 + w * 64 + n * 16 + ll) << 3));
#pragma unroll
        for (int m = 0; m < 4; ++m)
#pragma unroll
            for (int n = 0; n < 4; ++n)
                acc[m][n] = __builtin_amdgcn_mfma_f32_16x16x32_bf16(af[m], bfr[n], acc[m][n], 0, 0, 0);
    }

    // Epilogue: tanh + Watt dot, reduce over cols.
    // C layout (verified m89): row = (l>>4)*4 + j, col = l&15 within 16x16 frag.
    const int colb = w * 64 + ll;
    float watt[4];
#pragma unroll
    for (int n = 0; n < 4; ++n) watt[n] = Watt[colb + n * 16];

#pragma unroll
    for (int m = 0; m < 4; ++m) {
#pragma unroll
        for (int j = 0; j < 4; ++j) {
            int rl = m * 16 + lg * 4 + j;
            int rowg = r0 + rl;
            int b = rowg / NP;
            const float* db = dec + (size_t)b * ATT;
            float s = 0.f;
#pragma unroll
            for (int n = 0; n < 4; ++n)
                s += fast_tanh(acc[m][n][j] + db[colb + n * 16]) * watt[n];
            // reduce over the 16 lanes holding this row's 16 cols
            s += __shfl_xor(s, 1);
            s += __shfl_xor(s, 2);
            s += __shfl_xor(s, 4);
            s += __shfl_xor(s, 8);
            if (ll == 0) zred[rl * 8 + w] = s;
        }
    }
    __syncthreads();
    if (tid < 64) {
        float t = 0.f;
#pragma unroll
        for (int j = 0; j < 8; ++j) t += zred[tid * 8 + j];
        zt[r0 + tid] = t;
    }
}

// ---------------------------------------------------------------------------
// K3: per-b: out = tanh(dec+stw)@Watt ; alpha = softmax(zt) ; beta from
// softmax([zt, out]) last element. One block per b, 256 threads.
// ---------------------------------------------------------------------------
__global__ void k3_softmax(const float* __restrict__ dec, const float* __restrict__ stw,
                           const float* __restrict__ Watt, const float* __restrict__ zt,
                           float* __restrict__ out, float* __restrict__ beta_ws) {
    int b = blockIdx.x;
    int t = threadIdx.x;
    __shared__ float red[256];

    float p = 0.f;
#pragma unroll
    for (int c = t; c < ATT; c += 256)
        p += fast_tanh(dec[(size_t)b * ATT + c] + stw[(size_t)b * ATT + c]) * Watt[c];
    red[t] = p;
    __syncthreads();
    for (int s = 128; s > 0; s >>= 1) { if (t < s) red[t] += red[t + s]; __syncthreads(); }
    float outv = red[0];
    __syncthreads();

    float z = (t < NP) ? zt[b * NP + t] : -1e30f;
    red[t] = z;
    __syncthreads();
    for (int s = 128; s > 0; s >>= 1) { if (t < s) red[t] = fmaxf(red[t], red[t + s]); __syncthreads(); }
    float m1 = red[0];
    __syncthreads();

    float e = (t < NP) ? __expf(z - m1) : 0.f;
    red[t] = e;
    __syncthreads();
    for (int s = 128; s > 0; s >>= 1) { if (t < s) red[t] += red[t + s]; __syncthreads(); }
    float s1 = red[0];

    if (t < NP) out[b * NP + t] = e / s1;                       // alpha_t

    if (t == 0) {
        float m2 = fmaxf(m1, outv);
        float s2 = s1 * __expf(m1 - m2) + __expf(outv - m2);
        float beta = __expf(outv - m2) / s2;
        out[M_TOTAL + b] = beta;                                 // beta_t
        beta_ws[b] = beta;
    }
}

// ---------------------------------------------------------------------------
// K4: ct partials. grid (4 p-quarters, 256 b), block 256 (thread = 4 h).
// Deterministic: each (q,b) writes its own partial slab.
// ---------------------------------------------------------------------------
__global__ void k4_ct(const float* __restrict__ spatial, const float* __restrict__ alpha,
                      float* __restrict__ ctp) {
    int q = blockIdx.x;
    int b = blockIdx.y;
    int t = threadIdx.x;
    __shared__ float al[49];
    if (t < 49) al[t] = alpha[b * NP + q * 49 + t];
    __syncthreads();
    const float* sp = spatial + (size_t)b * NP * HIDDEN + (size_t)q * 49 * HIDDEN + t * 4;
    float4 acc = {0.f, 0.f, 0.f, 0.f};
#pragma unroll 7
    for (int p = 0; p < 49; ++p) {
        float4 v = *(const float4*)(sp + (size_t)p * HIDDEN);
        float a = al[p];
        acc.x += a * v.x; acc.y += a * v.y; acc.z += a * v.z; acc.w += a * v.w;
    }
    *(float4*)(ctp + ((size_t)q * BATCH + b) * HIDDEN + t * 4) = acc;
}

// ---------------------------------------------------------------------------
// K5: c_hat = beta*st + (1-beta)*ct  (sums the 4 ct partials)
// ---------------------------------------------------------------------------
__global__ void k5_chat(const float* __restrict__ st, const float* __restrict__ ctp,
                        const float* __restrict__ beta, float* __restrict__ chat) {
    int g = blockIdx.x * 256 + threadIdx.x;    // 65536 = 256 b * 256 h-quads
    int b = g >> 8;
    int h0 = (g & 255) * 4;
    float be = beta[b];
    float4 s = *(const float4*)(st + (size_t)b * HIDDEN + h0);
    float4 c = {0.f, 0.f, 0.f, 0.f};
#pragma unroll
    for (int q = 0; q < 4; ++q) {
        float4 v = *(const float4*)(ctp + ((size_t)q * BATCH + b) * HIDDEN + h0);
        c.x += v.x; c.y += v.y; c.z += v.z; c.w += v.w;
    }
    float4 o;
    o.x = be * s.x + (1.f - be) * c.x;
    o.y = be * s.y + (1.f - be) * c.y;
    o.z = be * s.z + (1.f - be) * c.z;
    o.w = be * s.w + (1.f - be) * c.w;
    *(float4*)(chat + (size_t)b * HIDDEN + h0) = o;
}

// ---------------------------------------------------------------------------
extern "C" void kernel_launch(void* const* d_in, const int* in_sizes, int n_in,
                              void* d_out, int out_size, void* d_ws, size_t ws_size,
                              hipStream_t stream) {
    const float* spatial = (const float*)d_in[0];   // (256,196,1024)
    const float* decoder = (const float*)d_in[1];   // (256,1024)
    const float* st      = (const float*)d_in[2];   // (256,1024)
    const float* Wcnn    = (const float*)d_in[3];   // (1024,512)
    const float* Wdec    = (const float*)d_in[4];   // (1024,512)
    const float* Wsen    = (const float*)d_in[5];   // (1024,512)
    const float* Watt    = (const float*)d_in[6];   // (512,1)
    float* out = (float*)d_out;   // alpha[50176] | beta[256] | c_hat[262144]

    char* ws = (char*)d_ws;
    unsigned short* Wt  = (unsigned short*)(ws + 0);        // 1 MB pre-tiled bf16 W_cnn
    float* zt   = (float*)(ws + 1048576);                   // 50176 f32
    float* dec  = (float*)(ws + 1249280);                   // 256x512
    float* stw  = (float*)(ws + 1773568);                   // 256x512
    float* beta = (float*)(ws + 2297856);                   // 256
    float* ctp  = (float*)(ws + 2298880);                   // 4x256x1024 partials

    k0_arrange<<<256, 256, 0, stream>>>(Wcnn, Wt);
    k1_small<<<dim3(4, 32, 2), 256, 0, stream>>>(decoder, st, Wdec, Wsen, dec, stw);
    k2_fused_gemm<<<784, 512, 0, stream>>>(spatial, Wt, dec, Watt, zt);
    k3_softmax<<<256, 256, 0, stream>>>(dec, stw, Watt, zt, out, beta);
    k4_ct<<<dim3(4, 256), 256, 0, stream>>>(spatial, out, ctp);
    k5_chat<<<256, 256, 0, stream>>>(st, ctp, beta, out + M_TOTAL + BATCH);
}

// Round 3
// 186.166 us; speedup vs baseline: 1.0339x; 1.0339x over previous
//
#include <hip/hip_runtime.h>
#include <hip/hip_bf16.h>

// Problem constants
#define BATCH   256
#define NP      196
#define HIDDEN  1024
#define ATT     512
#define M_TOTAL (BATCH * NP)   // 50176 rows
#define BM 128
#define BN 256
#define BK 32
#define MT_TILES (M_TOTAL / BM)   // 392
#define NB_TILES (ATT / BN)       // 2

typedef __attribute__((ext_vector_type(8))) short bf16x8v;  // 8 bf16 = 4 VGPR
typedef __attribute__((ext_vector_type(4))) float f32x4;

// f32 -> bf16 RNE (used only in K0 prep, cold path)
__device__ inline unsigned short f2bf(float x) {
    unsigned int u = __float_as_uint(x);
    u += 0x7fffu + ((u >> 16) & 1u);
    return (unsigned short)(u >> 16);
}

// packed f32 pair -> 2x bf16 in one uint via v_cvt_pk_bf16_f32
// (no HIP builtin on gfx950 — inline asm per guide T12/m240)
__device__ __forceinline__ unsigned int pk2bf(float lo, float hi) {
    unsigned int r;
    asm("v_cvt_pk_bf16_f32 %0, %1, %2" : "=v"(r) : "v"(lo), "v"(hi));
    return r;
}

__device__ inline float fast_tanh(float x) {
    float e = __expf(2.0f * x);
    return 1.0f - 2.0f / (e + 1.0f);
}

// async global->LDS, 16 bytes per lane. LDS dest must be uniform-base + lane*16.
__device__ __forceinline__ void glds16(const void* gsrc, void* ldst) {
    __builtin_amdgcn_global_load_lds(
        (const __attribute__((address_space(1))) unsigned int*)gsrc,
        (__attribute__((address_space(3))) unsigned int*)ldst,
        16, 0, 0);
}

// ---------------------------------------------------------------------------
// K0: W_cnn (f32 [1024][512]) -> bf16 tiled for K2's LDS B image:
//   Wt[nb 2][kt 32][chunk 4][n 256][8k]  — per (nb,kt) a contiguous 16 KB
//   image identical to the LDS Bbuf layout, so global_load_lds is a linear copy.
// ---------------------------------------------------------------------------
__global__ void k0_arrange(const float* __restrict__ Wc, unsigned short* __restrict__ Wt) {
    int g = blockIdx.x * 256 + threadIdx.x;   // 65536 slots of 8 bf16
    int nb    = g >> 15;
    int rem   = g & 32767;
    int kt    = rem >> 10;
    int chunk = (rem >> 8) & 3;
    int n     = rem & 255;
    int col   = nb * 256 + n;
    int kb    = kt * 32 + chunk * 8;
    unsigned short v[8];
#pragma unroll
    for (int j = 0; j < 8; ++j) v[j] = f2bf(Wc[(size_t)(kb + j) * ATT + col]);
    uint4 pk;
    pk.x = (unsigned int)v[0] | ((unsigned int)v[1] << 16);
    pk.y = (unsigned int)v[2] | ((unsigned int)v[3] << 16);
    pk.z = (unsigned int)v[4] | ((unsigned int)v[5] << 16);
    pk.w = (unsigned int)v[6] | ((unsigned int)v[7] << 16);
    *(uint4*)(Wt + (size_t)g * 8) = pk;
}

// ---------------------------------------------------------------------------
// K1: dec_out = decoder_out @ W_dec ; stw = st @ W_sen   (f32)
// ---------------------------------------------------------------------------
__global__ void k1_small(const float* __restrict__ dec_in, const float* __restrict__ st,
                         const float* __restrict__ Wdec,  const float* __restrict__ Wsen,
                         float* __restrict__ dec_out, float* __restrict__ stw) {
    const float* X = blockIdx.z ? st   : dec_in;
    const float* W = blockIdx.z ? Wsen : Wdec;
    float*       O = blockIdx.z ? stw  : dec_out;
    int ci = threadIdx.x & 31;
    int c0 = blockIdx.x * 128 + ci * 4;
    int b  = blockIdx.y * 8 + (threadIdx.x >> 5);
    const float* x = X + (size_t)b * HIDDEN;
    float4 acc = {0.f, 0.f, 0.f, 0.f};
    for (int k = 0; k < HIDDEN; k += 4) {
#pragma unroll
        for (int kk = 0; kk < 4; ++kk) {
            float4 w = *(const float4*)(W + (size_t)(k + kk) * ATT + c0);
            float a = x[k + kk];
            acc.x += a * w.x; acc.y += a * w.y; acc.z += a * w.z; acc.w += a * w.w;
        }
    }
    *(float4*)(O + (size_t)b * ATT + c0) = acc;
}

// ---------------------------------------------------------------------------
// K2: fused  zt_part[nb][r] = sum_{a in nb's 256 cols} tanh((A@Wc)[r,a]+dec)*Watt[a]
// m97-shape: tile 128x256, BK=32, 512 thr / 8 waves (2x4), wave = 64x64.
// B staged via global_load_lds (linear image from Wt). A reg-staged f32->bf16
// with one-k-tile prefetch. XCD-swizzled grid for A L2 reuse.
// ---------------------------------------------------------------------------
__global__ void __launch_bounds__(512, 4)
k2_fused_gemm(const float* __restrict__ A, const unsigned short* __restrict__ Wt,
              const float* __restrict__ dec, const float* __restrict__ Watt,
              float* __restrict__ ztp) {
    __shared__ __align__(16) unsigned short Abuf[4 * 128 * 8];   //  8 KB
    __shared__ __align__(16) unsigned short Bbuf[4 * 256 * 8];   // 16 KB
    __shared__ float zred[128 * 4];                              //  2 KB

    const int tid = threadIdx.x;
    const int w  = tid >> 6;
    const int l  = tid & 63;
    const int lg = l >> 4, ll = l & 15;
    const int wr = w >> 2, wc = w & 3;       // wave grid 2 (rows) x 4 (cols)

    // XCD-bijective swizzle: 784 blocks = 8 XCDs x 98. Same mt's two nb-blocks
    // are adjacent within an XCD chunk -> A tile L2 reuse.
    const int bid = (int)blockIdx.x;
    const int swz = (bid & 7) * 98 + (bid >> 3);
    const int mt = swz >> 1, nb = swz & 1;
    const int r0 = mt * BM;
    const int c0 = nb * BN;

    f32x4 acc[4][4];
#pragma unroll
    for (int m = 0; m < 4; ++m)
#pragma unroll
        for (int n = 0; n < 4; ++n) acc[m][n] = (f32x4){0.f, 0.f, 0.f, 0.f};

    // A staging: thread -> (row = tid>>2, chunk = tid&3): 8 consecutive k (32 B f32)
    const int arow = tid >> 2;
    const int ach  = tid & 3;
    const float* aptr = A + (size_t)(r0 + arow) * HIDDEN + ach * 8;
    unsigned short* aslot = Abuf + (ach * 128 + arow) * 8;

    // B staging: wave w stages parts w*2, w*2+1 (1 KB each, linear image copy)
    const size_t wt_base = (size_t)nb * 32 * 8192;   // elements
    const char* bsrc0 = (const char*)(Wt + wt_base) + (w * 2 + 0) * 1024 + l * 16;
    const char* bsrc1 = (const char*)(Wt + wt_base) + (w * 2 + 1) * 1024 + l * 16;
    char* bdst0 = (char*)Bbuf + (w * 2 + 0) * 1024 + l * 16;
    char* bdst1 = (char*)Bbuf + (w * 2 + 1) * 1024 + l * 16;

    // prologue: A regs for kt=0
    float4 a0 = *(const float4*)(aptr);
    float4 a1 = *(const float4*)(aptr + 4);

    for (int kt = 0; kt < 32; ++kt) {
        __syncthreads();   // previous tile fully consumed

        // B: async global->LDS (16 KB total, no VGPR round-trip)
        glds16(bsrc0 + kt * 16384, bdst0);
        glds16(bsrc1 + kt * 16384, bdst1);

        // A: convert this tile's registers -> LDS image
        uint4 ap;
        ap.x = pk2bf(a0.x, a0.y);
        ap.y = pk2bf(a0.z, a0.w);
        ap.z = pk2bf(a1.x, a1.y);
        ap.w = pk2bf(a1.z, a1.w);
        *(uint4*)aslot = ap;

        __syncthreads();   // tile visible (drains glds + lds writes)

        // prefetch next A tile (latency hides under ds_read + MFMA)
        if (kt < 31) {
            a0 = *(const float4*)(aptr + (kt + 1) * 32);
            a1 = *(const float4*)(aptr + (kt + 1) * 32 + 4);
        }

        bf16x8v af[4], bfr[4];
#pragma unroll
        for (int m = 0; m < 4; ++m)
            af[m] = *(const bf16x8v*)(Abuf + ((lg * 128 + wr * 64 + m * 16 + ll) << 3));
#pragma unroll
        for (int n = 0; n < 4; ++n)
            bfr[n] = *(const bf16x8v*)(Bbuf + ((lg * 256 + wc * 64 + n * 16 + ll) << 3));
#pragma unroll
        for (int m = 0; m < 4; ++m)
#pragma unroll
            for (int n = 0; n < 4; ++n)
                acc[m][n] = __builtin_amdgcn_mfma_f32_16x16x32_bf16(af[m], bfr[n], acc[m][n], 0, 0, 0);
    }

    // Epilogue: tanh + dec add + Watt dot; reduce this wave's 64 cols per row.
    // C frag layout: row = lg*4 + j, col = ll (m89-verified).
    const int clocal = wc * 64 + ll;
    float watt[4];
#pragma unroll
    for (int n = 0; n < 4; ++n) watt[n] = Watt[c0 + clocal + n * 16];

#pragma unroll
    for (int m = 0; m < 4; ++m) {
#pragma unroll
        for (int j = 0; j < 4; ++j) {
            int rl = wr * 64 + m * 16 + lg * 4 + j;
            int rowg = r0 + rl;
            int b = rowg / NP;
            const float* db = dec + (size_t)b * ATT + c0;
            float s = 0.f;
#pragma unroll
            for (int n = 0; n < 4; ++n)
                s += fast_tanh(acc[m][n][j] + db[clocal + n * 16]) * watt[n];
            s += __shfl_xor(s, 1);
            s += __shfl_xor(s, 2);
            s += __shfl_xor(s, 4);
            s += __shfl_xor(s, 8);
            if (ll == 0) zred[rl * 4 + wc] = s;
        }
    }
    __syncthreads();
    if (tid < 128) {
        float t = zred[tid * 4] + zred[tid * 4 + 1] + zred[tid * 4 + 2] + zred[tid * 4 + 3];
        ztp[(size_t)nb * M_TOTAL + r0 + tid] = t;
    }
}

// ---------------------------------------------------------------------------
// K3: per-b: out = tanh(dec+stw)@Watt ; alpha = softmax(zt) ; beta.
// zt = ztp[0] + ztp[1] (N-block partials).
// ---------------------------------------------------------------------------
__global__ void k3_softmax(const float* __restrict__ dec, const float* __restrict__ stw,
                           const float* __restrict__ Watt, const float* __restrict__ ztp,
                           float* __restrict__ out, float* __restrict__ beta_ws) {
    int b = blockIdx.x;
    int t = threadIdx.x;
    __shared__ float red[256];

    float p = 0.f;
#pragma unroll
    for (int c = t; c < ATT; c += 256)
        p += fast_tanh(dec[(size_t)b * ATT + c] + stw[(size_t)b * ATT + c]) * Watt[c];
    red[t] = p;
    __syncthreads();
    for (int s = 128; s > 0; s >>= 1) { if (t < s) red[t] += red[t + s]; __syncthreads(); }
    float outv = red[0];
    __syncthreads();

    float z = -1e30f;
    if (t < NP) z = ztp[b * NP + t] + ztp[M_TOTAL + b * NP + t];
    red[t] = z;
    __syncthreads();
    for (int s = 128; s > 0; s >>= 1) { if (t < s) red[t] = fmaxf(red[t], red[t + s]); __syncthreads(); }
    float m1 = red[0];
    __syncthreads();

    float e = (t < NP) ? __expf(z - m1) : 0.f;
    red[t] = e;
    __syncthreads();
    for (int s = 128; s > 0; s >>= 1) { if (t < s) red[t] += red[t + s]; __syncthreads(); }
    float s1 = red[0];

    if (t < NP) out[b * NP + t] = e / s1;                       // alpha_t

    if (t == 0) {
        float m2 = fmaxf(m1, outv);
        float s2 = s1 * __expf(m1 - m2) + __expf(outv - m2);
        float beta = __expf(outv - m2) / s2;
        out[M_TOTAL + b] = beta;                                 // beta_t
        beta_ws[b] = beta;
    }
}

// ---------------------------------------------------------------------------
// K4: ct partials. grid (4 p-quarters, 256 b), block 256 (thread = 4 h).
// ---------------------------------------------------------------------------
__global__ void k4_ct(const float* __restrict__ spatial, const float* __restrict__ alpha,
                      float* __restrict__ ctp) {
    int q = blockIdx.x;
    int b = blockIdx.y;
    int t = threadIdx.x;
    __shared__ float al[49];
    if (t < 49) al[t] = alpha[b * NP + q * 49 + t];
    __syncthreads();
    const float* sp = spatial + (size_t)b * NP * HIDDEN + (size_t)q * 49 * HIDDEN + t * 4;
    float4 acc = {0.f, 0.f, 0.f, 0.f};
#pragma unroll 7
    for (int p = 0; p < 49; ++p) {
        float4 v = *(const float4*)(sp + (size_t)p * HIDDEN);
        float a = al[p];
        acc.x += a * v.x; acc.y += a * v.y; acc.z += a * v.z; acc.w += a * v.w;
    }
    *(float4*)(ctp + ((size_t)q * BATCH + b) * HIDDEN + t * 4) = acc;
}

// ---------------------------------------------------------------------------
// K5: c_hat = beta*st + (1-beta)*ct  (sums the 4 ct partials)
// ---------------------------------------------------------------------------
__global__ void k5_chat(const float* __restrict__ st, const float* __restrict__ ctp,
                        const float* __restrict__ beta, float* __restrict__ chat) {
    int g = blockIdx.x * 256 + threadIdx.x;
    int b = g >> 8;
    int h0 = (g & 255) * 4;
    float be = beta[b];
    float4 s = *(const float4*)(st + (size_t)b * HIDDEN + h0);
    float4 c = {0.f, 0.f, 0.f, 0.f};
#pragma unroll
    for (int q = 0; q < 4; ++q) {
        float4 v = *(const float4*)(ctp + ((size_t)q * BATCH + b) * HIDDEN + h0);
        c.x += v.x; c.y += v.y; c.z += v.z; c.w += v.w;
    }
    float4 o;
    o.x = be * s.x + (1.f - be) * c.x;
    o.y = be * s.y + (1.f - be) * c.y;
    o.z = be * s.z + (1.f - be) * c.z;
    o.w = be * s.w + (1.f - be) * c.w;
    *(float4*)(chat + (size_t)b * HIDDEN + h0) = o;
}

// ---------------------------------------------------------------------------
extern "C" void kernel_launch(void* const* d_in, const int* in_sizes, int n_in,
                              void* d_out, int out_size, void* d_ws, size_t ws_size,
                              hipStream_t stream) {
    const float* spatial = (const float*)d_in[0];   // (256,196,1024)
    const float* decoder = (const float*)d_in[1];   // (256,1024)
    const float* st      = (const float*)d_in[2];   // (256,1024)
    const float* Wcnn    = (const float*)d_in[3];   // (1024,512)
    const float* Wdec    = (const float*)d_in[4];   // (1024,512)
    const float* Wsen    = (const float*)d_in[5];   // (1024,512)
    const float* Watt    = (const float*)d_in[6];   // (512,1)
    float* out = (float*)d_out;   // alpha[50176] | beta[256] | c_hat[262144]

    char* ws = (char*)d_ws;
    unsigned short* Wt = (unsigned short*)(ws + 0);   // 1 MB tiled bf16 W_cnn
    float* ztp  = (float*)(ws + 1048576);             // 2 x 50176 partials
    float* dec  = (float*)(ws + 1449984);             // 256x512
    float* stw  = (float*)(ws + 1974272);             // 256x512
    float* beta = (float*)(ws + 2498560);             // 256
    float* ctp  = (float*)(ws + 2499584);             // 4x256x1024 partials

    k0_arrange<<<256, 256, 0, stream>>>(Wcnn, Wt);
    k1_small<<<dim3(4, 32, 2), 256, 0, stream>>>(decoder, st, Wdec, Wsen, dec, stw);
    k2_fused_gemm<<<MT_TILES * NB_TILES, 512, 0, stream>>>(spatial, Wt, dec, Watt, ztp);
    k3_softmax<<<256, 256, 0, stream>>>(dec, stw, Watt, ztp, out, beta);
    k4_ct<<<dim3(4, 256), 256, 0, stream>>>(spatial, out, ctp);
    k5_chat<<<256, 256, 0, stream>>>(st, ctp, beta, out + M_TOTAL + BATCH);
}

// Round 4
// 173.127 us; speedup vs baseline: 1.1118x; 1.0753x over previous
//
#include <hip/hip_runtime.h>
#include <hip/hip_bf16.h>

// Problem constants
#define BATCH   256
#define NP      196
#define HIDDEN  1024
#define ATT     512
#define M_TOTAL (BATCH * NP)   // 50176 rows
#define BM 128
#define BN 256
#define BK 32
#define MT_TILES (M_TOTAL / BM)   // 392
#define NB_TILES (ATT / BN)       // 2

typedef __attribute__((ext_vector_type(8))) short bf16x8v;  // 8 bf16 = 4 VGPR
typedef __attribute__((ext_vector_type(4))) float f32x4;

// f32 -> bf16 RNE (used only in K0 prep, cold path)
__device__ inline unsigned short f2bf(float x) {
    unsigned int u = __float_as_uint(x);
    u += 0x7fffu + ((u >> 16) & 1u);
    return (unsigned short)(u >> 16);
}

// packed f32 pair -> 2x bf16 in one uint via v_cvt_pk_bf16_f32
__device__ __forceinline__ unsigned int pk2bf(float lo, float hi) {
    unsigned int r;
    asm("v_cvt_pk_bf16_f32 %0, %1, %2" : "=v"(r) : "v"(lo), "v"(hi));
    return r;
}

__device__ inline float fast_tanh(float x) {
    float e = __expf(2.0f * x);
    return 1.0f - 2.0f / (e + 1.0f);
}

// async global->LDS, 16 bytes per lane. LDS dest must be uniform-base + lane*16.
__device__ __forceinline__ void glds16(const void* gsrc, void* ldst) {
    __builtin_amdgcn_global_load_lds(
        (const __attribute__((address_space(1))) unsigned int*)gsrc,
        (__attribute__((address_space(3))) unsigned int*)ldst,
        16, 0, 0);
}

// ---------------------------------------------------------------------------
// K0: W_cnn (f32 [1024][512]) -> bf16 tiled for K2's LDS B image:
//   Wt[nb 2][kt 32][chunk 4][n 256][8k]  — per (nb,kt) a contiguous 16 KB
//   image identical to the LDS Bbuf layout, so global_load_lds is a linear copy.
// ---------------------------------------------------------------------------
__global__ void k0_arrange(const float* __restrict__ Wc, unsigned short* __restrict__ Wt) {
    int g = blockIdx.x * 256 + threadIdx.x;   // 65536 slots of 8 bf16
    int nb    = g >> 15;
    int rem   = g & 32767;
    int kt    = rem >> 10;
    int chunk = (rem >> 8) & 3;
    int n     = rem & 255;
    int col   = nb * 256 + n;
    int kb    = kt * 32 + chunk * 8;
    unsigned short v[8];
#pragma unroll
    for (int j = 0; j < 8; ++j) v[j] = f2bf(Wc[(size_t)(kb + j) * ATT + col]);
    uint4 pk;
    pk.x = (unsigned int)v[0] | ((unsigned int)v[1] << 16);
    pk.y = (unsigned int)v[2] | ((unsigned int)v[3] << 16);
    pk.z = (unsigned int)v[4] | ((unsigned int)v[5] << 16);
    pk.w = (unsigned int)v[6] | ((unsigned int)v[7] << 16);
    *(uint4*)(Wt + (size_t)g * 8) = pk;
}

// ---------------------------------------------------------------------------
// K1: dec_out = decoder_out @ W_dec ; stw = st @ W_sen   (f32)
// ---------------------------------------------------------------------------
__global__ void k1_small(const float* __restrict__ dec_in, const float* __restrict__ st,
                         const float* __restrict__ Wdec,  const float* __restrict__ Wsen,
                         float* __restrict__ dec_out, float* __restrict__ stw) {
    const float* X = blockIdx.z ? st   : dec_in;
    const float* W = blockIdx.z ? Wsen : Wdec;
    float*       O = blockIdx.z ? stw  : dec_out;
    int ci = threadIdx.x & 31;
    int c0 = blockIdx.x * 128 + ci * 4;
    int b  = blockIdx.y * 8 + (threadIdx.x >> 5);
    const float* x = X + (size_t)b * HIDDEN;
    float4 acc = {0.f, 0.f, 0.f, 0.f};
    for (int k = 0; k < HIDDEN; k += 4) {
#pragma unroll
        for (int kk = 0; kk < 4; ++kk) {
            float4 w = *(const float4*)(W + (size_t)(k + kk) * ATT + c0);
            float a = x[k + kk];
            acc.x += a * w.x; acc.y += a * w.y; acc.z += a * w.z; acc.w += a * w.w;
        }
    }
    *(float4*)(O + (size_t)b * ATT + c0) = acc;
}

// ---------------------------------------------------------------------------
// K2: fused  zt_part[nb][r] = sum_{a in nb's 256 cols} tanh((A@Wc)[r,a]+dec)*Watt[a]
// Tile 128x256, BK=32, 512 thr / 8 waves (2x4).
// DOUBLE-BUFFERED LDS + counted vmcnt (T3/T4-lite): one raw s_barrier per
// K-step with s_waitcnt vmcnt(2) — the 2 in-flight A prefetch loads span the
// barrier; B glds latency is covered by the compute phase.
// ---------------------------------------------------------------------------
__global__ void __launch_bounds__(512, 4)
k2_fused_gemm(const float* __restrict__ A, const unsigned short* __restrict__ Wt,
              const float* __restrict__ dec, const float* __restrict__ Watt,
              float* __restrict__ ztp) {
    __shared__ __align__(16) unsigned short Abuf[2][4 * 128 * 8];   // 2 x  8 KB
    __shared__ __align__(16) unsigned short Bbuf[2][4 * 256 * 8];   // 2 x 16 KB
    __shared__ float zred[128 * 4];                                 //  2 KB

    const int tid = threadIdx.x;
    const int w  = tid >> 6;
    const int l  = tid & 63;
    const int lg = l >> 4, ll = l & 15;
    const int wr = w >> 2, wc = w & 3;       // wave grid 2 (rows) x 4 (cols)

    // XCD-bijective swizzle: 784 blocks = 8 XCDs x 98; same mt's two nb-blocks
    // adjacent within an XCD chunk -> A tile L2 reuse.
    const int bid = (int)blockIdx.x;
    const int swz = (bid & 7) * 98 + (bid >> 3);
    const int mt = swz >> 1, nb = swz & 1;
    const int r0 = mt * BM;
    const int c0 = nb * BN;

    f32x4 acc[4][4];
#pragma unroll
    for (int m = 0; m < 4; ++m)
#pragma unroll
        for (int n = 0; n < 4; ++n) acc[m][n] = (f32x4){0.f, 0.f, 0.f, 0.f};

    // A staging: thread -> (row = tid>>2, chunk = tid&3): 8 consecutive k (32 B)
    const int arow = tid >> 2;
    const int ach  = tid & 3;
    const float* aptr = A + (size_t)(r0 + arow) * HIDDEN + ach * 8;
    const int aslot = (ach * 128 + arow) * 8;   // element index in one Abuf image

    // B staging: wave w stages a 2 KB span of the 16 KB tile image
    const size_t wt_base = (size_t)nb * 32 * 8192;   // elements
    const char* bsrc0 = (const char*)(Wt + wt_base) + w * 2048 + l * 16;
    const char* bsrc1 = bsrc0 + 1024;
    const int boff0 = w * 2048 + l * 16;             // byte offset in one Bbuf image
    const int boff1 = boff0 + 1024;

    // ---- Prologue: stage tile 0 into buf0; leave tile-1 A loads in flight ----
    glds16(bsrc0, (char*)Bbuf[0] + boff0);
    glds16(bsrc1, (char*)Bbuf[0] + boff1);
    float4 t0a = *(const float4*)(aptr);
    float4 t0b = *(const float4*)(aptr + 4);
    float4 aN0 = *(const float4*)(aptr + 32);   // tile 1, in flight across barrier
    float4 aN1 = *(const float4*)(aptr + 36);
    {
        uint4 ap;
        ap.x = pk2bf(t0a.x, t0a.y);
        ap.y = pk2bf(t0a.z, t0a.w);
        ap.z = pk2bf(t0b.x, t0b.y);
        ap.w = pk2bf(t0b.z, t0b.w);
        *(uint4*)(Abuf[0] + aslot) = ap;        // compiler waits t0 loads (vmcnt)
    }
    asm volatile("s_waitcnt vmcnt(2) lgkmcnt(0)" ::: "memory");  // B0 + A0 done; aN in flight
    __builtin_amdgcn_s_barrier();

    // ---- Main loop: iter kt computes tile kt from buf[kt&1], stages kt+1 ----
    for (int kt = 0; kt < 31; ++kt) {
        const int cur = kt & 1;
        const int nxt = cur ^ 1;

        // 1) stage B(kt+1) -> Bbuf[nxt]  (issued FIRST: covered by compute)
        glds16(bsrc0 + (size_t)(kt + 1) * 16384, (char*)Bbuf[nxt] + boff0);
        glds16(bsrc1 + (size_t)(kt + 1) * 16384, (char*)Bbuf[nxt] + boff1);

        // 2) issue A loads for kt+2 (clamped so exactly 2 vm ops stay in flight)
        const int kt2 = (kt + 2 < 32) ? (kt + 2) : 31;
        float4 aM0 = *(const float4*)(aptr + kt2 * 32);
        float4 aM1 = *(const float4*)(aptr + kt2 * 32 + 4);

        // 3) compute tile kt from buf[cur]
        bf16x8v af[4], bfr[4];
#pragma unroll
        for (int m = 0; m < 4; ++m)
            af[m] = *(const bf16x8v*)(Abuf[cur] + ((lg * 128 + wr * 64 + m * 16 + ll) << 3));
#pragma unroll
        for (int n = 0; n < 4; ++n)
            bfr[n] = *(const bf16x8v*)(Bbuf[cur] + ((lg * 256 + wc * 64 + n * 16 + ll) << 3));
#pragma unroll
        for (int m = 0; m < 4; ++m)
#pragma unroll
            for (int n = 0; n < 4; ++n)
                acc[m][n] = __builtin_amdgcn_mfma_f32_16x16x32_bf16(af[m], bfr[n], acc[m][n], 0, 0, 0);

        // 4) convert A(kt+1) -> Abuf[nxt] (compiler waits its loads: vmcnt(4))
        uint4 ap;
        ap.x = pk2bf(aN0.x, aN0.y);
        ap.y = pk2bf(aN0.z, aN0.w);
        ap.z = pk2bf(aN1.x, aN1.y);
        ap.w = pk2bf(aN1.z, aN1.w);
        *(uint4*)(Abuf[nxt] + aslot) = ap;
        aN0 = aM0; aN1 = aM1;

        // 5) barrier: B(kt+1) + A ds_write complete; A(kt+2) loads stay in flight
        asm volatile("s_waitcnt vmcnt(2) lgkmcnt(0)" ::: "memory");
        __builtin_amdgcn_s_barrier();
    }

    // ---- Final tile (kt=31) from buf[1], no staging ----
    {
        bf16x8v af[4], bfr[4];
#pragma unroll
        for (int m = 0; m < 4; ++m)
            af[m] = *(const bf16x8v*)(Abuf[1] + ((lg * 128 + wr * 64 + m * 16 + ll) << 3));
#pragma unroll
        for (int n = 0; n < 4; ++n)
            bfr[n] = *(const bf16x8v*)(Bbuf[1] + ((lg * 256 + wc * 64 + n * 16 + ll) << 3));
#pragma unroll
        for (int m = 0; m < 4; ++m)
#pragma unroll
            for (int n = 0; n < 4; ++n)
                acc[m][n] = __builtin_amdgcn_mfma_f32_16x16x32_bf16(af[m], bfr[n], acc[m][n], 0, 0, 0);
    }

    // Epilogue: tanh + dec add + Watt dot; reduce this wave's 64 cols per row.
    // C frag layout: row = lg*4 + j, col = ll (m89-verified).
    const int clocal = wc * 64 + ll;
    float watt[4];
#pragma unroll
    for (int n = 0; n < 4; ++n) watt[n] = Watt[c0 + clocal + n * 16];

#pragma unroll
    for (int m = 0; m < 4; ++m) {
#pragma unroll
        for (int j = 0; j < 4; ++j) {
            int rl = wr * 64 + m * 16 + lg * 4 + j;
            int rowg = r0 + rl;
            int b = rowg / NP;
            const float* db = dec + (size_t)b * ATT + c0;
            float s = 0.f;
#pragma unroll
            for (int n = 0; n < 4; ++n)
                s += fast_tanh(acc[m][n][j] + db[clocal + n * 16]) * watt[n];
            s += __shfl_xor(s, 1);
            s += __shfl_xor(s, 2);
            s += __shfl_xor(s, 4);
            s += __shfl_xor(s, 8);
            if (ll == 0) zred[rl * 4 + wc] = s;
        }
    }
    __syncthreads();
    if (tid < 128) {
        float t = zred[tid * 4] + zred[tid * 4 + 1] + zred[tid * 4 + 2] + zred[tid * 4 + 3];
        ztp[(size_t)nb * M_TOTAL + r0 + tid] = t;
    }
}

// ---------------------------------------------------------------------------
// K3: per-b: out = tanh(dec+stw)@Watt ; alpha = softmax(zt) ; beta.
// zt = ztp[0] + ztp[1] (N-block partials).
// ---------------------------------------------------------------------------
__global__ void k3_softmax(const float* __restrict__ dec, const float* __restrict__ stw,
                           const float* __restrict__ Watt, const float* __restrict__ ztp,
                           float* __restrict__ out, float* __restrict__ beta_ws) {
    int b = blockIdx.x;
    int t = threadIdx.x;
    __shared__ float red[256];

    float p = 0.f;
#pragma unroll
    for (int c = t; c < ATT; c += 256)
        p += fast_tanh(dec[(size_t)b * ATT + c] + stw[(size_t)b * ATT + c]) * Watt[c];
    red[t] = p;
    __syncthreads();
    for (int s = 128; s > 0; s >>= 1) { if (t < s) red[t] += red[t + s]; __syncthreads(); }
    float outv = red[0];
    __syncthreads();

    float z = -1e30f;
    if (t < NP) z = ztp[b * NP + t] + ztp[M_TOTAL + b * NP + t];
    red[t] = z;
    __syncthreads();
    for (int s = 128; s > 0; s >>= 1) { if (t < s) red[t] = fmaxf(red[t], red[t + s]); __syncthreads(); }
    float m1 = red[0];
    __syncthreads();

    float e = (t < NP) ? __expf(z - m1) : 0.f;
    red[t] = e;
    __syncthreads();
    for (int s = 128; s > 0; s >>= 1) { if (t < s) red[t] += red[t + s]; __syncthreads(); }
    float s1 = red[0];

    if (t < NP) out[b * NP + t] = e / s1;                       // alpha_t

    if (t == 0) {
        float m2 = fmaxf(m1, outv);
        float s2 = s1 * __expf(m1 - m2) + __expf(outv - m2);
        float beta = __expf(outv - m2) / s2;
        out[M_TOTAL + b] = beta;                                 // beta_t
        beta_ws[b] = beta;
    }
}

// ---------------------------------------------------------------------------
// K4: ct partials. grid (4 p-quarters, 256 b), block 256 (thread = 4 h).
// ---------------------------------------------------------------------------
__global__ void k4_ct(const float* __restrict__ spatial, const float* __restrict__ alpha,
                      float* __restrict__ ctp) {
    int q = blockIdx.x;
    int b = blockIdx.y;
    int t = threadIdx.x;
    __shared__ float al[49];
    if (t < 49) al[t] = alpha[b * NP + q * 49 + t];
    __syncthreads();
    const float* sp = spatial + (size_t)b * NP * HIDDEN + (size_t)q * 49 * HIDDEN + t * 4;
    float4 acc = {0.f, 0.f, 0.f, 0.f};
#pragma unroll 7
    for (int p = 0; p < 49; ++p) {
        float4 v = *(const float4*)(sp + (size_t)p * HIDDEN);
        float a = al[p];
        acc.x += a * v.x; acc.y += a * v.y; acc.z += a * v.z; acc.w += a * v.w;
    }
    *(float4*)(ctp + ((size_t)q * BATCH + b) * HIDDEN + t * 4) = acc;
}

// ---------------------------------------------------------------------------
// K5: c_hat = beta*st + (1-beta)*ct  (sums the 4 ct partials)
// ---------------------------------------------------------------------------
__global__ void k5_chat(const float* __restrict__ st, const float* __restrict__ ctp,
                        const float* __restrict__ beta, float* __restrict__ chat) {
    int g = blockIdx.x * 256 + threadIdx.x;
    int b = g >> 8;
    int h0 = (g & 255) * 4;
    float be = beta[b];
    float4 s = *(const float4*)(st + (size_t)b * HIDDEN + h0);
    float4 c = {0.f, 0.f, 0.f, 0.f};
#pragma unroll
    for (int q = 0; q < 4; ++q) {
        float4 v = *(const float4*)(ctp + ((size_t)q * BATCH + b) * HIDDEN + h0);
        c.x += v.x; c.y += v.y; c.z += v.z; c.w += v.w;
    }
    float4 o;
    o.x = be * s.x + (1.f - be) * c.x;
    o.y = be * s.y + (1.f - be) * c.y;
    o.z = be * s.z + (1.f - be) * c.z;
    o.w = be * s.w + (1.f - be) * c.w;
    *(float4*)(chat + (size_t)b * HIDDEN + h0) = o;
}

// ---------------------------------------------------------------------------
extern "C" void kernel_launch(void* const* d_in, const int* in_sizes, int n_in,
                              void* d_out, int out_size, void* d_ws, size_t ws_size,
                              hipStream_t stream) {
    const float* spatial = (const float*)d_in[0];   // (256,196,1024)
    const float* decoder = (const float*)d_in[1];   // (256,1024)
    const float* st      = (const float*)d_in[2];   // (256,1024)
    const float* Wcnn    = (const float*)d_in[3];   // (1024,512)
    const float* Wdec    = (const float*)d_in[4];   // (1024,512)
    const float* Wsen    = (const float*)d_in[5];   // (1024,512)
    const float* Watt    = (const float*)d_in[6];   // (512,1)
    float* out = (float*)d_out;   // alpha[50176] | beta[256] | c_hat[262144]

    char* ws = (char*)d_ws;
    unsigned short* Wt = (unsigned short*)(ws + 0);   // 1 MB tiled bf16 W_cnn
    float* ztp  = (float*)(ws + 1048576);             // 2 x 50176 partials
    float* dec  = (float*)(ws + 1449984);             // 256x512
    float* stw  = (float*)(ws + 1974272);             // 256x512
    float* beta = (float*)(ws + 2498560);             // 256
    float* ctp  = (float*)(ws + 2499584);             // 4x256x1024 partials

    k0_arrange<<<256, 256, 0, stream>>>(Wcnn, Wt);
    k1_small<<<dim3(4, 32, 2), 256, 0, stream>>>(decoder, st, Wdec, Wsen, dec, stw);
    k2_fused_gemm<<<MT_TILES * NB_TILES, 512, 0, stream>>>(spatial, Wt, dec, Watt, ztp);
    k3_softmax<<<256, 256, 0, stream>>>(dec, stw, Watt, ztp, out, beta);
    k4_ct<<<dim3(4, 256), 256, 0, stream>>>(spatial, out, ctp);
    k5_chat<<<256, 256, 0, stream>>>(st, ctp, beta, out + M_TOTAL + BATCH);
}